// Round 9
// baseline (269.924 us; speedup 1.0000x reference)
//
#include <hip/hip_runtime.h>
#include <hip/hip_bf16.h>

#define NB 16
#define SS 2048
#define DD 64
#define GRID 512

typedef __attribute__((ext_vector_type(8))) short short8;
typedef __attribute__((ext_vector_type(4))) float f32x4;

// SCALE * log2(e), folded so softmax exp is one v_mul + one v_exp
#define SCL2E 0.18033688011112042f

// partial slot: 64x64 acc + 64 l, padded
#define PSLOT 4224

// round-to-nearest-even f32 -> bf16 (as raw short)
__device__ __forceinline__ short f2bf(float f) {
  union { float f; unsigned u; } v; v.f = f;
  unsigned r = (v.u + 0x7fffu + ((v.u >> 16) & 1u)) >> 16;
  return (short)r;
}

__device__ __forceinline__ short8 load_a_frag_f32(const float* p) {
  float4 u = *(const float4*)p;
  float4 w = *(const float4*)(p + 4);
  short8 r;
  r[0] = f2bf(u.x); r[1] = f2bf(u.y); r[2] = f2bf(u.z); r[3] = f2bf(u.w);
  r[4] = f2bf(w.x); r[5] = f2bf(w.y); r[6] = f2bf(w.z); r[7] = f2bf(w.w);
  return r;
}

// device-scope grid barrier (all GRID blocks co-resident by construction:
// grid == 2 blocks/CU under __launch_bounds__(256,2))
__device__ __forceinline__ void gridbar(unsigned* cnt) {
  __syncthreads();
  if (threadIdx.x == 0) {
    __threadfence();                     // release: prior stores device-visible
    atomicAdd(cnt, 1u);
    while (atomicAdd(cnt, 0u) < GRID)
      __builtin_amdgcn_s_sleep(2);
    __threadfence();                     // acquire: invalidate stale caches
  }
  __syncthreads();
}

// ---------------------------------------------------------------------------
// Phase A: QKV projection (R8 proj body). Block bid handles 64 seq rows.
// ---------------------------------------------------------------------------
__device__ void proj_body(int bid, int t,
    const float* __restrict__ x,
    const float* __restrict__ Wq, const float* __restrict__ bq,
    const float* __restrict__ Wk, const float* __restrict__ bk,
    const float* __restrict__ Wv, const float* __restrict__ bv,
    ushort* __restrict__ qo, ushort* __restrict__ ko, ushort* __restrict__ vT,
    ushort* Wt, ushort* Vs)   // Wt: [3][64][72], Vs: [64][72] in LDS
{
  {
    const float* Ws[3] = {Wq, Wk, Wv};
    for (int m = 0; m < 3; ++m)
      for (int i = 0; i < 4; ++i) {
        int idx = i * 1024 + t * 4;
        int kk = idx >> 6, n0 = idx & 63;
        float4 w4 = *(const float4*)(Ws[m] + kk * 64 + n0);
        Wt[m * 4608 + (n0 + 0) * 72 + kk] = (ushort)f2bf(w4.x);
        Wt[m * 4608 + (n0 + 1) * 72 + kk] = (ushort)f2bf(w4.y);
        Wt[m * 4608 + (n0 + 2) * 72 + kk] = (ushort)f2bf(w4.z);
        Wt[m * 4608 + (n0 + 3) * 72 + kk] = (ushort)f2bf(w4.w);
      }
  }
  __syncthreads();

  const int lane = t & 63, w = t >> 6;
  const int l15 = lane & 15, quad = lane >> 4;
  const int g = bid * 64 + w * 16 + l15;
  short8 a0 = load_a_frag_f32(x + (size_t)g * 64 + quad * 8);
  short8 a1 = load_a_frag_f32(x + (size_t)g * 64 + 32 + quad * 8);
  const int lrow0 = w * 16 + quad * 4;

  for (int m = 0; m < 3; ++m) {
    const float* bp = (m == 0 ? bq : (m == 1 ? bk : bv));
#pragma unroll
    for (int nt = 0; nt < 4; ++nt) {
      short8 b0 = *(const short8*)&Wt[m * 4608 + (nt * 16 + l15) * 72 + quad * 8];
      short8 b1 = *(const short8*)&Wt[m * 4608 + (nt * 16 + l15) * 72 + 32 + quad * 8];
      f32x4 acc = {0.f, 0.f, 0.f, 0.f};
      acc = __builtin_amdgcn_mfma_f32_16x16x32_bf16(a0, b0, acc, 0, 0, 0);
      acc = __builtin_amdgcn_mfma_f32_16x16x32_bf16(a1, b1, acc, 0, 0, 0);
      float bb = bp[nt * 16 + l15];
#pragma unroll
      for (int r = 0; r < 4; ++r)
        Vs[(lrow0 + r) * 72 + nt * 16 + l15] = (ushort)f2bf(acc[r] + bb);
    }
    __syncthreads();
    if (m < 2) {
      ushort* outp = (m == 0 ? qo : ko);
      const int row = t >> 2, col0 = (t & 3) * 16;
      int4 d0 = *(const int4*)&Vs[row * 72 + col0];
      int4 d1 = *(const int4*)&Vs[row * 72 + col0 + 8];
      ushort* dst = outp + (size_t)(bid * 64 + row) * 64 + col0;
      ((int4*)dst)[0] = d0;
      ((int4*)dst)[1] = d1;
      __syncthreads();   // Vs reused next m
    } else {
      const int batch = bid >> 5;
      const int s0 = (bid & 31) * 64;
      const int d = t >> 2, j0 = (t & 3) * 16;
      ushort tmp[16];
      for (int j = 0; j < 16; ++j) tmp[j] = Vs[(j0 + j) * 72 + d];
      ushort* dst = vT + (size_t)batch * DD * SS + (size_t)d * SS + s0 + j0;
      ((int4*)dst)[0] = ((int4*)tmp)[0];
      ((int4*)dst)[1] = ((int4*)tmp)[1];
    }
  }
}

// ---------------------------------------------------------------------------
// exp + packed P write + PV for one 16-query group. Key interleave: c[ct] at
// lane l15 is key kb + 4*l15 + ct. MASKED compile-time.
// ---------------------------------------------------------------------------
template<bool MASKED>
__device__ __forceinline__ void attn_half(
    const f32x4 (&c)[4], float (&l_part)[4], f32x4 (&acc)[4],
    const short8 (&vf0)[4], const short8 (&vf1)[4],
    ushort* __restrict__ Pw, int kb4, int rowb, int l15, int quad)
{
#pragma unroll
  for (int r = 0; r < 4; ++r) {
    float pe[4];
#pragma unroll
    for (int ct = 0; ct < 4; ++ct) {
      pe[ct] = __builtin_amdgcn_exp2f(c[ct][r] * SCL2E);
      if (MASKED && (kb4 + ct > rowb + r)) pe[ct] = 0.f;
    }
    l_part[r] += (pe[0] + pe[1]) + (pe[2] + pe[3]);
    __hip_bfloat162 h01 = __float22bfloat162_rn(make_float2(pe[0], pe[1]));
    __hip_bfloat162 h23 = __float22bfloat162_rn(make_float2(pe[2], pe[3]));
    uint2 pwv;
    pwv.x = *reinterpret_cast<unsigned*>(&h01);
    pwv.y = *reinterpret_cast<unsigned*>(&h23);
    *(uint2*)&Pw[(quad * 4 + r) * 72 + 4 * l15] = pwv;
  }
  short8 pa0 = *(const short8*)&Pw[l15 * 72 + quad * 8];
  short8 pa1 = *(const short8*)&Pw[l15 * 72 + 32 + quad * 8];
#pragma unroll
  for (int nt = 0; nt < 4; ++nt) {
    acc[nt] = __builtin_amdgcn_mfma_f32_16x16x32_bf16(pa0, vf0[nt], acc[nt], 0, 0, 0);
    acc[nt] = __builtin_amdgcn_mfma_f32_16x16x32_bf16(pa1, vf1[nt], acc[nt], 0, 0, 0);
  }
}

// ---------------------------------------------------------------------------
// Phase B: one wave item = (batch, 64q tile qt, chunk c of <=4 key tiles).
// R8 body, wave-independent, no barriers.
// ---------------------------------------------------------------------------
__device__ void attn_item(int gitem, int lane, ushort* __restrict__ Pw,
    const ushort* __restrict__ qg, const ushort* __restrict__ kg,
    const ushort* __restrict__ vT, float* __restrict__ pws,
    float* __restrict__ out)
{
  const int l15 = lane & 15, quad = lane >> 4;
  const int batch = gitem & 15;
  const int u = gitem >> 4;                   // 0..255
  const int qt = u >> 3;                      // 64q tile, 0..31
  const int c = u & 7;                        // chunk
  const int nkt = qt + 1;
  const int t0 = 4 * c;
  if (t0 >= nkt) return;                      // zombie item
  const int tend = min(t0 + 4, nkt);

  const int q0 = qt * 64;
  const size_t bbase = (size_t)batch * SS * DD;

  short8 a0[4], a1[4];
#pragma unroll
  for (int g = 0; g < 4; ++g) {
    const ushort* qp = qg + bbase + (size_t)(q0 + g * 16 + l15) * 64 + quad * 8;
    a0[g] = *(const short8*)qp;
    a1[g] = *(const short8*)(qp + 32);
  }

  f32x4 acc[4][4];
  float lp[4][4];
#pragma unroll
  for (int g = 0; g < 4; ++g)
#pragma unroll
    for (int nt = 0; nt < 4; ++nt) {
      acc[g][nt] = (f32x4){0.f, 0.f, 0.f, 0.f};
      lp[g][nt] = 0.f;
    }

  const ushort* kpc = kg + bbase + (size_t)(4 * l15) * 64 + quad * 8
                    + (size_t)t0 * 4096;
  const ushort* vp0 = vT + bbase + (size_t)l15 * SS + t0 * 64 + quad * 8;
  const ushort* vp1 = vp0 + 16 * SS;
  const ushort* vp2 = vp0 + 32 * SS;
  const ushort* vp3 = vp0 + 48 * SS;

  short8 kc0[4], kc1[4];
#pragma unroll
  for (int ct = 0; ct < 4; ++ct) {
    kc0[ct] = *(const short8*)(kpc + ct * 64);
    kc1[ct] = *(const short8*)(kpc + ct * 64 + 32);
  }

  const int kend_nm = (tend == nkt) ? (nkt - 1) : tend;

  for (int kt = t0; kt < kend_nm; ++kt) {
    short8 vf0[4], vf1[4];
    vf0[0] = *(const short8*)(vp0); vf1[0] = *(const short8*)(vp0 + 32);
    vf0[1] = *(const short8*)(vp1); vf1[1] = *(const short8*)(vp1 + 32);
    vf0[2] = *(const short8*)(vp2); vf1[2] = *(const short8*)(vp2 + 32);
    vf0[3] = *(const short8*)(vp3); vf1[3] = *(const short8*)(vp3 + 32);

    short8 kn0[4], kn1[4];
#pragma unroll
    for (int ct = 0; ct < 4; ++ct) {
      kn0[ct] = *(const short8*)(kpc + 4096 + ct * 64);
      kn1[ct] = *(const short8*)(kpc + 4096 + ct * 64 + 32);
    }

    const int kb4 = kt * 64 + 4 * l15;
#pragma unroll
    for (int g = 0; g < 4; ++g) {
      f32x4 cc[4];
#pragma unroll
      for (int ct = 0; ct < 4; ++ct) {
        cc[ct] = (f32x4){0.f, 0.f, 0.f, 0.f};
        cc[ct] = __builtin_amdgcn_mfma_f32_16x16x32_bf16(a0[g], kc0[ct], cc[ct], 0, 0, 0);
        cc[ct] = __builtin_amdgcn_mfma_f32_16x16x32_bf16(a1[g], kc1[ct], cc[ct], 0, 0, 0);
      }
      attn_half<false>(cc, lp[g], acc[g], vf0, vf1, Pw, kb4,
                       q0 + g * 16 + quad * 4, l15, quad);
    }

#pragma unroll
    for (int ct = 0; ct < 4; ++ct) { kc0[ct] = kn0[ct]; kc1[ct] = kn1[ct]; }
    kpc += 4096;
    vp0 += 64; vp1 += 64; vp2 += 64; vp3 += 64;
  }

  if (tend == nkt) {   // masked diagonal tile
    short8 vf0[4], vf1[4];
    vf0[0] = *(const short8*)(vp0); vf1[0] = *(const short8*)(vp0 + 32);
    vf0[1] = *(const short8*)(vp1); vf1[1] = *(const short8*)(vp1 + 32);
    vf0[2] = *(const short8*)(vp2); vf1[2] = *(const short8*)(vp2 + 32);
    vf0[3] = *(const short8*)(vp3); vf1[3] = *(const short8*)(vp3 + 32);

    const int kb4 = (nkt - 1) * 64 + 4 * l15;
#pragma unroll
    for (int g = 0; g < 4; ++g) {
      f32x4 cc[4];
#pragma unroll
      for (int ct = 0; ct < 4; ++ct) {
        cc[ct] = (f32x4){0.f, 0.f, 0.f, 0.f};
        cc[ct] = __builtin_amdgcn_mfma_f32_16x16x32_bf16(a0[g], kc0[ct], cc[ct], 0, 0, 0);
        cc[ct] = __builtin_amdgcn_mfma_f32_16x16x32_bf16(a1[g], kc1[ct], cc[ct], 0, 0, 0);
      }
      attn_half<true>(cc, lp[g], acc[g], vf0, vf1, Pw, kb4,
                      q0 + g * 16 + quad * 4, l15, quad);
    }
  }

#pragma unroll
  for (int g = 0; g < 4; ++g)
#pragma unroll
    for (int r = 0; r < 4; ++r)
      for (int off = 1; off < 16; off <<= 1)
        lp[g][r] += __shfl_xor(lp[g][r], off, 64);

  if (nkt <= 4) {
    float* ob = out + bbase;
#pragma unroll
    for (int g = 0; g < 4; ++g) {
      float iv[4];
#pragma unroll
      for (int r = 0; r < 4; ++r) iv[r] = 1.0f / lp[g][r];
#pragma unroll
      for (int r = 0; r < 4; ++r)
#pragma unroll
        for (int nt = 0; nt < 4; ++nt)
          ob[(size_t)(q0 + g * 16 + quad * 4 + r) * 64 + nt * 16 + l15] =
              acc[g][nt][r] * iv[r];
    }
  } else {
    float* ps = pws + (size_t)(((batch << 5) + qt) * 8 + c) * PSLOT;
#pragma unroll
    for (int g = 0; g < 4; ++g) {
#pragma unroll
      for (int r = 0; r < 4; ++r)
#pragma unroll
        for (int nt = 0; nt < 4; ++nt)
          ps[(g * 16 + quad * 4 + r) * 64 + nt * 16 + l15] = acc[g][nt][r];
      if (l15 == 0)
#pragma unroll
        for (int r = 0; r < 4; ++r)
          ps[4096 + g * 16 + quad * 4 + r] = lp[g][r];
    }
  }
}

// ---------------------------------------------------------------------------
// Phase C: combine partials for qt >= 4 (448 block-items).
// ---------------------------------------------------------------------------
__device__ void combine_body(int bid, int t, float* inv_s,
    const float* __restrict__ pws, float* __restrict__ out)
{
  const int batch = bid & 15, qt = 4 + (bid >> 4);
  const int q0 = qt * 64;
  const int nch = (qt + 4) >> 2;
  const float* ps0 = pws + (size_t)(((batch << 5) + qt) * 8) * PSLOT;

  if (t < 64) {
    float d = 0.f;
    for (int c = 0; c < nch; ++c) d += ps0[c * PSLOT + 4096 + t];
    inv_s[t] = 1.0f / d;
  }
  __syncthreads();

  const int row = t >> 2, col0 = (t & 3) * 16;
  float4 o[4];
#pragma unroll
  for (int i = 0; i < 4; ++i) o[i] = (float4){0.f, 0.f, 0.f, 0.f};
  for (int c = 0; c < nch; ++c) {
    const float* pr = ps0 + c * PSLOT + row * 64 + col0;
#pragma unroll
    for (int i = 0; i < 4; ++i) {
      float4 xv = *(const float4*)(pr + i * 4);
      o[i].x += xv.x; o[i].y += xv.y; o[i].z += xv.z; o[i].w += xv.w;
    }
  }
  float iv = inv_s[row];
  float* op = out + (size_t)batch * SS * DD + (size_t)(q0 + row) * 64 + col0;
#pragma unroll
  for (int i = 0; i < 4; ++i) {
    o[i].x *= iv; o[i].y *= iv; o[i].z *= iv; o[i].w *= iv;
    *(float4*)(op + i * 4) = o[i];
  }
}

// ---------------------------------------------------------------------------
// Fused persistent kernel: proj -> gridbar -> attn (2 items/wave) -> gridbar
// -> combine. GRID = 512 = 2 blocks/CU (co-resident by __launch_bounds__).
// ---------------------------------------------------------------------------
__global__ __launch_bounds__(256, 2) void fused_kernel(
    const float* __restrict__ x,
    const float* __restrict__ Wq, const float* __restrict__ bq,
    const float* __restrict__ Wk, const float* __restrict__ bk,
    const float* __restrict__ Wv, const float* __restrict__ bv,
    ushort* __restrict__ qws, ushort* __restrict__ kws, ushort* __restrict__ vws,
    float* __restrict__ pws, float* __restrict__ out, unsigned* __restrict__ bar)
{
  __shared__ __align__(16) ushort smem[18432];   // 36864 B
  ushort* Wt = smem;                 // proj: [3][64][72]
  ushort* Vs = smem + 13824;         // proj: [64][72]
  float* inv_s = (float*)smem;       // combine: [64]

  const int t = threadIdx.x, bid = blockIdx.x;
  const int w = t >> 6, lane = t & 63;

  // ---- Phase A: projection ----
  proj_body(bid, t, x, Wq, bq, Wk, bk, Wv, bv, qws, kws, vws, Wt, Vs);

  gridbar(&bar[0]);

  // ---- Phase B: attention (wave-independent items) ----
  ushort* Pw = smem + w * (16 * 72);
  const int wid = bid * 4 + w;                   // 0..2047
  attn_item(wid,        lane, Pw, qws, kws, vws, pws, out);
  attn_item(wid + 2048, lane, Pw, qws, kws, vws, pws, out);

  gridbar(&bar[16]);

  // ---- Phase C: combine ----
  if (bid < 448)
    combine_body(bid, t, inv_s, pws, out);
}

extern "C" void kernel_launch(void* const* d_in, const int* in_sizes, int n_in,
                              void* d_out, int out_size, void* d_ws, size_t ws_size,
                              hipStream_t stream) {
  (void)in_sizes; (void)n_in; (void)out_size; (void)ws_size;
  const float* x  = (const float*)d_in[0];
  const float* Wq = (const float*)d_in[1];
  const float* bq = (const float*)d_in[2];
  const float* Wk = (const float*)d_in[3];
  const float* bk = (const float*)d_in[4];
  const float* Wv = (const float*)d_in[5];
  const float* bv = (const float*)d_in[6];
  float* out = (float*)d_out;

  unsigned char* ws = (unsigned char*)d_ws;
  unsigned* bar = (unsigned*)ws;                       // 256 B barrier region
  ushort* qws = (ushort*)(ws + 256);                   // bf16 q: 4 MB
  ushort* kws = qws + (size_t)NB * SS * DD;            // bf16 k: 4 MB
  ushort* vws = kws + (size_t)NB * SS * DD;            // bf16 v^T: 4 MB
  float* pws = (float*)(vws + (size_t)NB * SS * DD);   // partials: ~69 MB

  hipMemsetAsync(bar, 0, 256, stream);
  fused_kernel<<<dim3(GRID), dim3(256), 0, stream>>>(
      x, Wq, bq, Wk, bk, Wv, bv, qws, kws, vws, pws, out, bar);
}